// Round 3
// baseline (634.494 us; speedup 1.0000x reference)
//
#include <hip/hip_runtime.h>
#include <hip/hip_bf16.h>

#define HW 9216
#define CDIM 256
#define NBATCH 8
#define NHEADS 8

typedef __bf16 bf16x8 __attribute__((ext_vector_type(8)));
typedef float f32x4 __attribute__((ext_vector_type(4)));

__device__ inline unsigned short f2bf(float f) {
    unsigned int u = __builtin_bit_cast(unsigned int, f);
    u = (u + 0x7FFF + ((u >> 16) & 1)) >> 16;
    return (unsigned short)u;
}
__device__ inline float bf2f(unsigned short s) {
    unsigned int u = ((unsigned int)s) << 16;
    return __builtin_bit_cast(float, u);
}
__device__ inline unsigned int pk2(float a, float b) {
    return (unsigned int)f2bf(a) | ((unsigned int)f2bf(b) << 16);
}
__device__ inline float ldx(const float* p) { return *p; }
__device__ inline float ldx(const unsigned short* p) { return bf2f(*p); }
__device__ inline void stx(float* p, float v) { *p = v; }
__device__ inline void stx(unsigned short* p, float v) { *p = f2bf(v); }

// ---------------- fuse W_cat @ [W_qr; W_qd] -> bf16 Wq [256][512], fp32 bq ----------------
__global__ void fuse_wq(const float* __restrict__ W_cat, const float* __restrict__ W_qr,
                        const float* __restrict__ W_qd, const float* __restrict__ b_qr,
                        const float* __restrict__ b_qd, const float* __restrict__ b_cat,
                        unsigned short* __restrict__ Wq, float* __restrict__ bq) {
    int o = blockIdx.x;
    int c = threadIdx.x;
    float ax = 0.f, ay = 0.f;
    for (int i = 0; i < 128; ++i) {
        ax += W_cat[o * 256 + i] * W_qr[i * 256 + c];
        ay += W_cat[o * 256 + 128 + i] * W_qd[i * 256 + c];
    }
    Wq[o * 512 + c] = f2bf(ax);
    Wq[o * 512 + 256 + c] = f2bf(ay);
    if (c == 0) {
        float s = b_cat[o];
        for (int i = 0; i < 128; ++i)
            s += W_cat[o * 256 + i] * b_qr[i] + W_cat[o * 256 + 128 + i] * b_qd[i];
        bq[o] = s;
    }
}

// ---------------- stack + convert W_kf, W_vf -> Wkv [512][256] bf16, bkv [512] ----------------
__global__ void cvt_wkv(const float* __restrict__ W_kf, const float* __restrict__ W_vf,
                        const float* __restrict__ b_kf, const float* __restrict__ b_vf,
                        unsigned short* __restrict__ Wkv, float* __restrict__ bkv) {
    int o = blockIdx.x;   // 0..511
    int c = threadIdx.x;
    const float* src = (o < 256) ? &W_kf[(size_t)o * 256] : &W_vf[(size_t)(o - 256) * 256];
    Wkv[(size_t)o * 256 + c] = f2bf(src[c]);
    if (c == 0) bkv[o] = (o < 256) ? b_kf[o] : b_vf[o - 256];
}

// ---------------- MFMA conv1x1 GEMM, software-pipelined ----------------
// Out[b,m,n] = sum_k A[m,k]*X[b,k,n] + bias[m] (+resid). A bf16 [M][Ktot] (batch stride a_bs).
// X = X0 for k<256, X1 for k>=256 (q-GEMM K=512). If split_off!=0, rows m>=256 write to
// Out+split_off (fused k/v GEMM). Block tile 128x128, 4 waves of 64x64, BK=32.
template <typename TX, typename TOut>
__global__ __launch_bounds__(256) void gemm_mfma(
    const unsigned short* __restrict__ A, int a_bs, int Ktot,
    const TX* __restrict__ X0, const TX* __restrict__ X1,
    const float* __restrict__ bias, const float* __restrict__ resid,
    TOut* __restrict__ Out, size_t split_off) {
    const int b = blockIdx.z;
    const int n0 = blockIdx.x * 128;
    const int m0 = blockIdx.y * 128;
    const int tid = threadIdx.x;
    const int lane = tid & 63;
    const int wid = tid >> 6;
    const int wm = (wid >> 1) * 64;
    const int wn = (wid & 1) * 64;
    const int l15 = lane & 15;
    const int quad = lane >> 4;

    // double-buffered B tile in fragment order: [kquad(4)][n(128)][j(8)] bf16 = 8 KB each
    __shared__ __align__(16) unsigned short Bs[2][4 * 128 * 8];

    const unsigned short* Ab = A + (size_t)b * a_bs;
    const TX* Xb0 = X0 + (size_t)b * CDIM * HW;
    const TX* Xb1 = X1 ? X1 + (size_t)b * CDIM * HW : nullptr;

    f32x4 acc[4][4] = {};

    const int sn = tid & 127;           // staged n within tile
    const int sq0 = (tid >> 7) * 2;     // staged kquad pair

    int arow[4];
#pragma unroll
    for (int mi = 0; mi < 4; ++mi)
        arow[mi] = (m0 + wm + mi * 16 + l15) * Ktot + quad * 8;

    const int nkt = Ktot >> 5;          // 8 or 16, always even

    float fA[2][8], fB[2][8];
    bf16x8 af[4], af2[4];

    // ---- prologue: issue loads for k-step 0 ----
#pragma unroll
    for (int qq = 0; qq < 2; ++qq) {
        const TX* src = Xb0 + (size_t)((sq0 + qq) * 8) * HW + n0 + sn;
#pragma unroll
        for (int j = 0; j < 8; ++j) fA[qq][j] = ldx(src + (size_t)j * HW);
    }
#pragma unroll
    for (int mi = 0; mi < 4; ++mi) af[mi] = *(const bf16x8*)(Ab + arow[mi]);

    auto step = [&](int kt, float (&fc)[2][8], float (&fn)[2][8],
                    bf16x8 (&ac)[4], bf16x8 (&an)[4], int bsel) {
        // pack current staged regs -> LDS (waits on their vmcnt here)
#pragma unroll
        for (int qq = 0; qq < 2; ++qq) {
            uint4 pk;
            pk.x = pk2(fc[qq][0], fc[qq][1]);
            pk.y = pk2(fc[qq][2], fc[qq][3]);
            pk.z = pk2(fc[qq][4], fc[qq][5]);
            pk.w = pk2(fc[qq][6], fc[qq][7]);
            *(uint4*)&Bs[bsel][((sq0 + qq) * 128 + sn) * 8] = pk;
        }
        __syncthreads();

        // issue next k-step's global loads; they drain behind the MFMAs below
        if (kt + 1 < nkt) {
            int k0n = (kt + 1) * 32;
            const TX* Xp = (k0n < 256) ? Xb0 : Xb1;
            int k0r = k0n & 255;
#pragma unroll
            for (int qq = 0; qq < 2; ++qq) {
                const TX* src = Xp + (size_t)(k0r + (sq0 + qq) * 8) * HW + n0 + sn;
#pragma unroll
                for (int j = 0; j < 8; ++j) fn[qq][j] = ldx(src + (size_t)j * HW);
            }
#pragma unroll
            for (int mi = 0; mi < 4; ++mi)
                an[mi] = *(const bf16x8*)(Ab + arow[mi] + k0n);
        }

        bf16x8 bfr[4];
#pragma unroll
        for (int nj = 0; nj < 4; ++nj)
            bfr[nj] = *(const bf16x8*)&Bs[bsel][(quad * 128 + wn + nj * 16 + l15) * 8];

#pragma unroll
        for (int mi = 0; mi < 4; ++mi)
#pragma unroll
            for (int nj = 0; nj < 4; ++nj)
                acc[mi][nj] = __builtin_amdgcn_mfma_f32_16x16x32_bf16(ac[mi], bfr[nj], acc[mi][nj], 0, 0, 0);
    };

    for (int kt = 0; kt < nkt; kt += 2) {
        step(kt, fA, fB, af, af2, 0);
        step(kt + 1, fB, fA, af2, af, 1);
    }

    // ---- epilogue: C/D layout col(n)=lane&15, row(m)=quad*4+reg ----
#pragma unroll
    for (int mi = 0; mi < 4; ++mi) {
#pragma unroll
        for (int r = 0; r < 4; ++r) {
            int m = m0 + wm + mi * 16 + quad * 4 + r;
            float bv = bias[m];
            size_t base_off = ((m >= 256) ? split_off : 0) + ((size_t)b * CDIM + (m & 255)) * HW;
#pragma unroll
            for (int nj = 0; nj < 4; ++nj) {
                int n = n0 + wn + nj * 16 + l15;
                size_t off = base_off + n;
                float v = acc[mi][nj][r] + bv;
                if (resid) v += resid[off];
                stx(&Out[off], v);
            }
        }
    }
}

// ---------------- Gram + sum-of-squares (per b,h; chunked over n, atomic accumulate) ----
__global__ __launch_bounds__(256) void gram_kernel(
    const unsigned short* __restrict__ q, const unsigned short* __restrict__ k,
    float* __restrict__ G, float* __restrict__ sqq, float* __restrict__ sqk) {
    const int nc = blockIdx.x;   // 72 chunks of 128
    const int h = blockIdx.y, b = blockIdx.z;
    const int t = threadIdx.x;

    __shared__ float qs[32][128];
    __shared__ float ks[32][129];

    size_t base = ((size_t)b * CDIM + h * 32) * HW + nc * 128;
#pragma unroll
    for (int i = 0; i < 4; ++i) {
        int idx = i * 256 + t;
        int row = idx >> 5, c4 = (idx & 31) * 4;
        ushort4 qv = *(const ushort4*)&q[base + (size_t)row * HW + c4];
        ushort4 kv = *(const ushort4*)&k[base + (size_t)row * HW + c4];
        qs[row][c4 + 0] = bf2f(qv.x); qs[row][c4 + 1] = bf2f(qv.y);
        qs[row][c4 + 2] = bf2f(qv.z); qs[row][c4 + 3] = bf2f(qv.w);
        ks[row][c4 + 0] = bf2f(kv.x); ks[row][c4 + 1] = bf2f(kv.y);
        ks[row][c4 + 2] = bf2f(kv.z); ks[row][c4 + 3] = bf2f(kv.w);
    }
    __syncthreads();

    const int d = t & 31;
    const int cb = t >> 5;
    float acc[4] = {0.f, 0.f, 0.f, 0.f};
    for (int n = 0; n < 128; ++n) {
        float kv = ks[d][n];
#pragma unroll
        for (int p = 0; p < 4; ++p) acc[p] += qs[cb + 8 * p][n] * kv;
    }

    float* Gp = G + (size_t)(b * 8 + h) * 32 * 32;
#pragma unroll
    for (int p = 0; p < 4; ++p) atomicAdd(&Gp[(cb + 8 * p) * 32 + d], acc[p]);

    // sum-of-squares: thread t handles channel c=t&31, n-slice part=t>>5 (16 n each)
    {
        int c = t & 31, part = t >> 5;
        float s1 = 0.f, s2 = 0.f;
#pragma unroll
        for (int n = part * 16; n < part * 16 + 16; ++n) {
            float a = qs[c][n]; s1 += a * a;
            float e = ks[c][n]; s2 += e * e;
        }
        atomicAdd(&sqq[(b * 8 + h) * 32 + c], s1);
        atomicAdd(&sqk[(b * 8 + h) * 32 + c], s2);
    }
}

// ---------------- normalize + temperature + softmax ----------------
__global__ __launch_bounds__(1024) void softmax_kernel(
    const float* __restrict__ G, const float* __restrict__ sqq,
    const float* __restrict__ sqk, const float* __restrict__ temp,
    float* __restrict__ A) {
    int bh = blockIdx.x;
    int h = bh & 7;
    int c = threadIdx.y, d = threadIdx.x;
    float nq = fmaxf(sqrtf(sqq[bh * 32 + c]), 1e-12f);
    float nk = fmaxf(sqrtf(sqk[bh * 32 + d]), 1e-12f);
    float v = G[(size_t)(bh * 32 + c) * 32 + d] / (nq * nk) * temp[h];
    float m = v;
    for (int s = 16; s > 0; s >>= 1) m = fmaxf(m, __shfl_xor(m, s, 32));
    float e = __expf(v - m);
    float sum = e;
    for (int s = 16; s > 0; s >>= 1) sum += __shfl_xor(sum, s, 32);
    A[(size_t)(bh * 32 + c) * 32 + d] = e / sum;
}

// ---------------- M_b[o, h*32+d] = sum_c W_proj[o, h*32+c] * A[b,h,c,d] -> bf16 ----------------
__global__ __launch_bounds__(256) void build_m(const float* __restrict__ W_proj,
                                               const float* __restrict__ A,
                                               unsigned short* __restrict__ M) {
    int o = blockIdx.x;
    int b = blockIdx.y;
    int t = threadIdx.x;
    int h = t >> 5, d = t & 31;
    const float* Ab = A + (size_t)(b * 8 + h) * 32 * 32;
    float acc = 0.f;
    for (int c = 0; c < 32; ++c)
        acc += W_proj[o * 256 + h * 32 + c] * Ab[c * 32 + d];
    M[((size_t)b * 256 + o) * 256 + t] = f2bf(acc);
}

extern "C" void kernel_launch(void* const* d_in, const int* in_sizes, int n_in,
                              void* d_out, int out_size, void* d_ws, size_t ws_size,
                              hipStream_t stream) {
    const float* x = (const float*)d_in[0];
    const float* y = (const float*)d_in[1];
    const float* z = (const float*)d_in[2];
    const float* W_qr = (const float*)d_in[3];
    const float* b_qr = (const float*)d_in[4];
    const float* W_qd = (const float*)d_in[5];
    const float* b_qd = (const float*)d_in[6];
    const float* W_kf = (const float*)d_in[7];
    const float* b_kf = (const float*)d_in[8];
    const float* W_vf = (const float*)d_in[9];
    const float* b_vf = (const float*)d_in[10];
    const float* W_cat = (const float*)d_in[11];
    const float* b_cat = (const float*)d_in[12];
    const float* W_proj = (const float*)d_in[13];
    const float* b_proj = (const float*)d_in[14];
    const float* temp = (const float*)d_in[15];
    float* out = (float*)d_out;

    char* ws = (char*)d_ws;
    const size_t NT = (size_t)NBATCH * CDIM * HW;  // elements per tensor
    unsigned short* qb = (unsigned short*)ws;
    unsigned short* kb = qb + NT;
    unsigned short* vb = kb + NT;   // vb = kb + NT: contiguous, enables split write
    char* p = (char*)(vb + NT);
    unsigned short* Wq  = (unsigned short*)p;  p += 256 * 512 * 2;
    unsigned short* Wkv = (unsigned short*)p;  p += 512 * 256 * 2;
    float* bq  = (float*)p;                    p += 1024;
    float* bkv = (float*)p;                    p += 2048;
    float* G   = (float*)p;                    p += 64 * 32 * 32 * 4;
    float* sqq = (float*)p;                    p += 2048 * 4;
    float* sqk = (float*)p;                    p += 2048 * 4;
    float* Aat = (float*)p;                    p += 64 * 32 * 32 * 4;
    unsigned short* Mb = (unsigned short*)p;   p += (size_t)8 * 256 * 256 * 2;

    // zero the atomic accumulators (G, sqq, sqk contiguous)
    hipMemsetAsync(G, 0, 262144 + 8192 + 8192, stream);

    fuse_wq<<<256, 256, 0, stream>>>(W_cat, W_qr, W_qd, b_qr, b_qd, b_cat, Wq, bq);
    cvt_wkv<<<512, 256, 0, stream>>>(W_kf, W_vf, b_kf, b_vf, Wkv, bkv);

    // q = [Wqx|Wqy] @ [x;y]  (M=256, K=512)
    gemm_mfma<float, unsigned short><<<dim3(HW / 128, 2, NBATCH), 256, 0, stream>>>(
        Wq, 0, 512, x, y, bq, nullptr, qb, 0);
    // [k;v] = [Wk;Wv] @ z  (M=512, K=256, split write kb/vb)
    gemm_mfma<float, unsigned short><<<dim3(HW / 128, 4, NBATCH), 256, 0, stream>>>(
        Wkv, 0, 256, z, nullptr, bkv, nullptr, kb, NT);

    gram_kernel<<<dim3(HW / 128, NHEADS, NBATCH), 256, 0, stream>>>(qb, kb, G, sqq, sqk);
    softmax_kernel<<<64, dim3(32, 32), 0, stream>>>(G, sqq, sqk, temp, Aat);
    build_m<<<dim3(256, 8), 256, 0, stream>>>(W_proj, Aat, Mb);

    // out = M_b @ v + b_proj + z  (M=256, K=256)
    gemm_mfma<unsigned short, float><<<dim3(HW / 128, 2, NBATCH), 256, 0, stream>>>(
        Mb, 256 * 256, 256, vb, nullptr, b_proj, z, out, 0);
}